// Round 7
// baseline (324.342 us; speedup 1.0000x reference)
//
#include <hip/hip_runtime.h>
#include <stdint.h>

#define NPTS 100000
#define KNEI 16
#define CIN 64
#define CMID 32
#define CONC 64
#define LINI 1024
#define COUT 128
#define APITCH 1032   // u16 per aggL row (keeps b128 16B alignment; spread verified)

typedef unsigned short u16;
typedef unsigned int u32;
typedef __attribute__((ext_vector_type(8))) short bf16x8;
typedef __attribute__((ext_vector_type(4))) float f32x4;

// ws layout (bytes):
//   [0, 6400000)            feats2: u32[N][16], channel-paired (c | c+16<<16)
//   [WS_PACKB, +131072)     packed lin_w bf16 (65536 elems, MFMA B-frag order)
//   [WS_PACKW2, +32768)     packed [u2_w; sc_w] bf16 (16384 elems, B-frag order)
//   [WS_WN, +576)           folded WeightNet: W23[8][16] fp32, b23[16] fp32
#define WS_PACKB  6400000
#define WS_PACKW2 (WS_PACKB + 131072)
#define WS_WN     (WS_PACKW2 + 32768)

#define NB_U1 391             // ceil(NPTS/256); 256 points per block (64/wave, MFMA path)
#define NB_PACK 256
#define NB_PACKW2 64

__device__ __forceinline__ float lrelu(float x) { return fmaxf(x, 0.1f * x); }

// exact RNE (one-time prep only)
__device__ __forceinline__ u32 f2bf(float f) {
    union { float f; u32 u; } v; v.f = f;
    return (v.u + 0x7FFFu + ((v.u >> 16) & 1u)) >> 16;
}
// fast round-half-up, scalar
__device__ __forceinline__ u16 f2bfF(float f) {
    union { float f; u32 u; } v; v.f = f;
    return (u16)((v.u + 0x8000u) >> 16);
}
// fast round-half-up, packed pair (low=a, high=b)
__device__ __forceinline__ u32 pkbf(float a, float b) {
    union { float f; u32 u; } x, y; x.f = a; y.f = b;
    return __builtin_amdgcn_perm(y.u + 0x8000u, x.u + 0x8000u, 0x07060302u);
}
__device__ __forceinline__ float bf2f(u32 h) {
    union { u32 u; float f; } v; v.u = h << 16; return v.f;
}

// ---- merged prep: u1 feats via MFMA (paired) + pack lin_w + pack W2 + fold WeightNet ----
__global__ __launch_bounds__(256) void k_prep(
    const float* __restrict__ df, const float* __restrict__ u1_w,
    const float* __restrict__ u1_b, u32* __restrict__ feats2,
    const float* __restrict__ lin_w, u16* __restrict__ packB,
    const float* __restrict__ u2_w, const float* __restrict__ sc_w,
    u16* __restrict__ packW2,
    const float* __restrict__ wn_w2, const float* __restrict__ wn_b2,
    const float* __restrict__ wn_w3, const float* __restrict__ wn_b3,
    float* __restrict__ wnf)
{
    int bid = blockIdx.x;
    if (bid < NB_U1) {
        // u1 GEMM: per wave, 4 groups of feats[16 pts][32 ch] = df[16][64] @ u1_w[64][32] + b.
        // bw B-frags built ONCE per 64 points (amortized 4x vs per-16).
        const int wv = threadIdx.x >> 6, lane = threadIdx.x & 63;
        const int quad = lane >> 4, nl = lane & 15;
        const int base = bid * 256 + wv * 64;
        if (base >= NPTS) return;

        bf16x8 bw[2][2];   // [nt][kk]
        #pragma unroll
        for (int nt = 0; nt < 2; ++nt)
            #pragma unroll
            for (int kk = 0; kk < 2; ++kk)
                #pragma unroll
                for (int j = 0; j < 8; ++j)
                    bw[nt][kk][j] = (short)f2bf(u1_w[(kk * 32 + quad * 8 + j) * CMID + nt * 16 + nl]);

        float blo = u1_b[nl], bhi = u1_b[16 + nl];
        const f32x4 z = {0.f, 0.f, 0.f, 0.f};

        #pragma unroll
        for (int g = 0; g < 4; ++g) {
            int pbase = base + g * 16;
            if (pbase >= NPTS) break;

            const float* arow = df + (size_t)(pbase + nl) * CIN + quad * 8;
            float4 a0 = *(const float4*)(arow + 0);
            float4 a1 = *(const float4*)(arow + 4);
            float4 a2 = *(const float4*)(arow + 32);
            float4 a3 = *(const float4*)(arow + 36);
            bf16x8 afr0, afr1;
            u32* ap0 = (u32*)&afr0; u32* ap1 = (u32*)&afr1;
            ap0[0] = pkbf(a0.x, a0.y); ap0[1] = pkbf(a0.z, a0.w);
            ap0[2] = pkbf(a1.x, a1.y); ap0[3] = pkbf(a1.z, a1.w);
            ap1[0] = pkbf(a2.x, a2.y); ap1[1] = pkbf(a2.z, a2.w);
            ap1[2] = pkbf(a3.x, a3.y); ap1[3] = pkbf(a3.z, a3.w);

            f32x4 acc0 = z, acc1 = z;
            acc0 = __builtin_amdgcn_mfma_f32_16x16x32_bf16(afr0, bw[0][0], acc0, 0, 0, 0);
            acc0 = __builtin_amdgcn_mfma_f32_16x16x32_bf16(afr1, bw[0][1], acc0, 0, 0, 0);
            acc1 = __builtin_amdgcn_mfma_f32_16x16x32_bf16(afr0, bw[1][0], acc1, 0, 0, 0);
            acc1 = __builtin_amdgcn_mfma_f32_16x16x32_bf16(afr1, bw[1][1], acc1, 0, 0, 0);

            #pragma unroll
            for (int r = 0; r < 4; ++r) {
                int pt = pbase + quad * 4 + r;
                feats2[(size_t)pt * 16 + nl] = f2bf(acc0[r] + blo) | (f2bf(acc1[r] + bhi) << 16);
            }
        }
    } else if (bid < NB_U1 + NB_PACK) {
        int t = (bid - NB_U1) * 256 + threadIdx.x;     // 65536 total
        int j = t & 7, ln = (t >> 3) & 63, s = t >> 9;
        int nt = s & 3, kb = s >> 2;
        int k = kb * 32 + (ln >> 4) * 8 + j;
        int n = nt * 16 + (ln & 15);
        packB[t] = (u16)f2bf(lin_w[k * 64 + n]);
    } else if (bid < NB_U1 + NB_PACK + NB_PACKW2) {
        int t = (bid - NB_U1 - NB_PACK) * 256 + threadIdx.x;   // 16384 total
        int j = t & 7, ln = (t >> 3) & 63, s = t >> 9;
        int nt2 = s & 7, kb2 = s >> 3;
        int k = kb2 * 32 + (ln >> 4) * 8 + j;
        int n = nt2 * 16 + (ln & 15);
        float v = (k < 64) ? u2_w[k * COUT + n] : sc_w[(k - 64) * COUT + n];
        packW2[t] = (u16)f2bf(v);
    } else {
        int t = threadIdx.x;
        if (t < 128) {
            int i = t >> 4, o = t & 15;
            float a = 0.f;
            #pragma unroll
            for (int m = 0; m < 8; ++m) a += wn_w2[i * 8 + m] * wn_w3[m * 16 + o];
            wnf[i * 16 + o] = a;
        } else if (t < 144) {
            int o = t - 128;
            float a = wn_b3[o];
            #pragma unroll
            for (int m = 0; m < 8; ++m) a += wn_b2[m] * wn_w3[m * 16 + o];
            wnf[128 + o] = a;
        }
    }
}

// ---- Fused: gather/PE/WN/einsum (phase 1) + GEMM1 + GEMM2 (phase 2). ----
// Block = 256 threads; TWO groups of 16 points per block (amortizes weight preload).
__global__ __launch_bounds__(256) void k_fused(
    const float* __restrict__ xyz, const int* __restrict__ nei,
    const u32* __restrict__ feats2,
    const float* __restrict__ pe_w1, const float* __restrict__ pe_b1,
    const float* __restrict__ pe_w2, const float* __restrict__ pe_b2,
    const float* __restrict__ wn_w1, const float* __restrict__ wn_b1,
    const float* __restrict__ wnf,
    const u16* __restrict__ packB, const u16* __restrict__ packW2,
    const float* __restrict__ lin_b,
    const float* __restrict__ u2_b, const float* __restrict__ sc_b,
    const float* __restrict__ df, float* __restrict__ out,
    float* __restrict__ locout)
{
    __shared__ __align__(16) u16 aggL[16 * APITCH];   // 33,024 B
    __shared__ float loc_s[4][4][16][3];              //  3,072 B (wave-private)
    __shared__ int   idx_s[4][4][16];                 //  1,024 B (wave-private)
    __shared__ __align__(16) u16 pexd[4][32][24];     //  6,144 B; pe in ph1, xd in ph2
    __shared__ __align__(16) u16 w_s[4][16][24];      //  3,072 B (wave-private)
    __shared__ __align__(16) u16 h1_s[4][4][16][8];   //  4,096 B bf16 h1 per (p,k)

    u16* xd = &pexd[0][0][0];                         // phase-2 alias (4 KB used)

    const int tid = threadIdx.x, wv = tid >> 6, lane = tid & 63;
    const int quad = lane >> 4, nl = lane & 15;

    // ---- preload per-lane weights (once per block, serves both groups) ----
    float w1r0[8], w1r1[8], w1r2[8], b1v[8];
    #pragma unroll
    for (int j = 0; j < 8; ++j) {
        int h = quad * 8 + j;
        w1r0[j] = pe_w1[h]; w1r1[j] = pe_w1[32 + h]; w1r2[j] = pe_w1[64 + h];
        b1v[j] = pe_b1[h];
    }
    bf16x8 w2t[2];
    #pragma unroll
    for (int ct = 0; ct < 2; ++ct)
        #pragma unroll
        for (int j = 0; j < 8; ++j)
            w2t[ct][j] = (short)f2bf(pe_w2[(quad * 8 + j) * 32 + nl + 16 * ct]);
    float b2v[2][4];
    #pragma unroll
    for (int ct = 0; ct < 2; ++ct)
        #pragma unroll
        for (int r = 0; r < 4; ++r)
            b2v[ct][r] = pe_b2[16 * ct + quad * 4 + r];
    float wn3v[8][4], b23v[4];
    #pragma unroll
    for (int h = 0; h < 8; ++h)
        #pragma unroll
        for (int r = 0; r < 4; ++r)
            wn3v[h][r] = wnf[h * 16 + quad * 4 + r];
    #pragma unroll
    for (int r = 0; r < 4; ++r) b23v[r] = wnf[128 + quad * 4 + r];

    const f32x4 zacc = {0.f, 0.f, 0.f, 0.f};

    for (int g = 0; g < 2; ++g) {
        if (g) __syncthreads();   // prior group's GEMM2 (xd reads) before pexd reuse
        const int p0 = blockIdx.x * 32 + g * 16;

        // ---- phase 1, step 0: coords + indices + deduped h1 (lane: point=quad, k=nl) ----
        int pt0 = p0 + wv * 4 + quad;
        int idx0 = nei[pt0 * KNEI + nl];
        idx_s[wv][quad][nl] = idx0;
        {
            float cx = xyz[pt0 * 3 + 0], cy = xyz[pt0 * 3 + 1], cz = xyz[pt0 * 3 + 2];
            float lx0 = xyz[idx0 * 3 + 0] - cx;
            float ly0 = xyz[idx0 * 3 + 1] - cy;
            float lz0 = xyz[idx0 * 3 + 2] - cz;
            loc_s[wv][quad][nl][0] = lx0;
            loc_s[wv][quad][nl][1] = ly0;
            loc_s[wv][quad][nl][2] = lz0;
            float3 lv; lv.x = lx0; lv.y = ly0; lv.z = lz0;
            *(float3*)(locout + (size_t)(pt0 * KNEI + nl) * 3) = lv;
            // WeightNet layer-1 (only nonlinearity before the fold), bf16-packed
            uint4 hp;
            u32* hpp = (u32*)&hp;
            #pragma unroll
            for (int h = 0; h < 8; h += 2) {
                float a = lrelu(wn_b1[h]     + lx0 * wn_w1[h]     + ly0 * wn_w1[8 + h]     + lz0 * wn_w1[16 + h]);
                float b = lrelu(wn_b1[h + 1] + lx0 * wn_w1[h + 1] + ly0 * wn_w1[8 + h + 1] + lz0 * wn_w1[16 + h + 1]);
                hpp[h >> 1] = pkbf(a, b);
            }
            *(uint4*)&h1_s[wv][quad][nl][0] = hp;
        }

        for (int p = 0; p < 4; ++p) {
            const int m = wv * 4 + p;   // block-local point row

            // ---- paired feats gather into B-frags via v_perm (quads 0,1; 2,3 zero) ----
            bf16x8 featf0 = 0, featf1 = 0;
            if (quad < 2) {
                u32 gv[8];
                #pragma unroll
                for (int j = 0; j < 8; ++j) {
                    int idk = idx_s[wv][p][quad * 8 + j];
                    gv[j] = feats2[(size_t)idk * 16 + nl];
                }
                u32* f0w = (u32*)&featf0;
                u32* f1w = (u32*)&featf1;
                #pragma unroll
                for (int jp = 0; jp < 4; ++jp) {
                    u32 a = gv[2 * jp], b = gv[2 * jp + 1];
                    f0w[jp] = __builtin_amdgcn_perm(b, a, 0x05040100u);   // lo16(a)|lo16(b)<<16
                    f1w[jp] = __builtin_amdgcn_perm(b, a, 0x07060302u);   // hi16(a)|hi16(b)<<16
                }
            }

            float lx = loc_s[wv][p][nl][0];
            float ly = loc_s[wv][p][nl][1];
            float lz = loc_s[wv][p][nl][2];

            // ---- B1: ph in B-frag layout (h=quad*8+j, k_nei=nl) ----
            bf16x8 phf;
            {
                u32* ph32 = (u32*)&phf;
                #pragma unroll
                for (int j = 0; j < 8; j += 2) {
                    float v0 = lrelu(b1v[j]     + lx * w1r0[j]     + ly * w1r1[j]     + lz * w1r2[j]);
                    float v1 = lrelu(b1v[j + 1] + lx * w1r0[j + 1] + ly * w1r1[j + 1] + lz * w1r2[j + 1]);
                    ph32[j >> 1] = pkbf(v0, v1);
                }
            }

            // ---- B2: pe^T = w2^T @ ph : 2 MFMAs ----
            f32x4 pe0 = __builtin_amdgcn_mfma_f32_16x16x32_bf16(w2t[0], phf, zacc, 0, 0, 0);
            f32x4 pe1 = __builtin_amdgcn_mfma_f32_16x16x32_bf16(w2t[1], phf, zacc, 0, 0, 0);

            #pragma unroll
            for (int r = 0; r < 4; ++r) {
                pexd[wv][quad * 4 + r][nl]      = f2bfF(lrelu(pe0[r] + b2v[0][r]));
                pexd[wv][16 + quad * 4 + r][nl] = f2bfF(lrelu(pe1[r] + b2v[1][r]));
            }

            // ---- folded WeightNet output (h1 from LDS broadcast, W23 in regs) ----
            {
                uint4 hv = *(const uint4*)&h1_s[wv][p][nl][0];
                float h1f[8];
                h1f[0] = bf2f(hv.x & 0xffffu); h1f[1] = bf2f(hv.x >> 16);
                h1f[2] = bf2f(hv.y & 0xffffu); h1f[3] = bf2f(hv.y >> 16);
                h1f[4] = bf2f(hv.z & 0xffffu); h1f[5] = bf2f(hv.z >> 16);
                h1f[6] = bf2f(hv.w & 0xffffu); h1f[7] = bf2f(hv.w >> 16);
                #pragma unroll
                for (int r = 0; r < 4; ++r) {
                    float a = b23v[r];
                    #pragma unroll
                    for (int h = 0; h < 8; ++h) a += h1f[h] * wn3v[h][r];
                    w_s[wv][quad * 4 + r][nl] = f2bfF(lrelu(a));
                }
            }
            // wave-private LDS: intra-wave ordering via lgkmcnt; no block barrier.

            // ---- read frags: wA (A: o=nl, k=quad*8+j), peB (B: k, c=nl) ----
            bf16x8 wA = 0, peB0 = 0, peB1 = 0;
            if (quad < 2) {
                wA   = *(const bf16x8*)&w_s[wv][nl][quad * 8];
                peB0 = *(const bf16x8*)&pexd[wv][nl][quad * 8];
                peB1 = *(const bf16x8*)&pexd[wv][nl + 16][quad * 8];
            }

            // ---- einsum: D[o][c] = w^T @ nf, 4 c-tiles, K=16 (padded) ----
            f32x4 c0a = __builtin_amdgcn_mfma_f32_16x16x32_bf16(wA, featf0, zacc, 0, 0, 0);
            f32x4 c1a = __builtin_amdgcn_mfma_f32_16x16x32_bf16(wA, featf1, zacc, 0, 0, 0);
            f32x4 c2a = __builtin_amdgcn_mfma_f32_16x16x32_bf16(wA, peB0, zacc, 0, 0, 0);
            f32x4 c3a = __builtin_amdgcn_mfma_f32_16x16x32_bf16(wA, peB1, zacc, 0, 0, 0);

            // ---- store agg row into LDS (plain layout, pitch 1032) ----
            {
                u16* arow = aggL + m * APITCH;
                f32x4 cc[4] = {c0a, c1a, c2a, c3a};
                #pragma unroll
                for (int ct = 0; ct < 4; ++ct) {
                    int e = (nl + 16 * ct) * 16 + quad * 4;
                    uint2 o;
                    o.x = pkbf(cc[ct][0], cc[ct][1]);
                    o.y = pkbf(cc[ct][2], cc[ct][3]);
                    *(uint2*)(arow + e) = o;
                }
            }
        }
        __syncthreads();   // all aggL rows visible; pe region now dead -> xd

        // ================= phase 2 =================
        // GEMM1: x[16][64] = lrelu(agg @ lin_w + lin_b); wave wv owns n-tile nt=wv.
        const int nt = wv;
        {
            const u16* bp = packB + nt * 512 + lane * 8;
            const u16* arow = aggL + nl * APITCH;
            f32x4 accA = zacc, accB = zacc;
            #pragma unroll
            for (int kk = 0; kk < 16; ++kk) {
                int kbA = 2 * kk, kbB = 2 * kk + 1;
                bf16x8 aA = *(const bf16x8*)(arow + (4 * kbA + quad) * 8);
                bf16x8 aB = *(const bf16x8*)(arow + (4 * kbB + quad) * 8);
                bf16x8 bA = *(const bf16x8*)(bp + kbA * 2048);
                bf16x8 bB = *(const bf16x8*)(bp + kbB * 2048);
                accA = __builtin_amdgcn_mfma_f32_16x16x32_bf16(aA, bA, accA, 0, 0, 0);
                accB = __builtin_amdgcn_mfma_f32_16x16x32_bf16(aB, bB, accB, 0, 0, 0);
            }
            int col = nt * 16 + nl;
            float lb = lin_b[col];
            int kb2 = col >> 5, q2 = (col >> 3) & 3, j2 = col & 7;
            #pragma unroll
            for (int r = 0; r < 4; ++r) {
                int mm = quad * 4 + r;
                float v = lrelu(accA[r] + accB[r] + lb);
                xd[(kb2 * 64 + q2 * 16 + mm) * 8 + j2] = f2bfF(v);
            }
        }
        // df -> xd (cols 64..127)
        if (tid < 128) {
            int mm = tid >> 3, cg = tid & 7;
            int colk = 64 + cg * 8;
            const float* dfr = df + (size_t)(p0 + mm) * CIN + cg * 8;
            float4 f0 = *(const float4*)(dfr);
            float4 f1 = *(const float4*)(dfr + 4);
            int kb2 = colk >> 5, q2 = (colk >> 3) & 3;
            uint4 o;
            o.x = pkbf(f0.x, f0.y);
            o.y = pkbf(f0.z, f0.w);
            o.z = pkbf(f1.x, f1.y);
            o.w = pkbf(f1.z, f1.w);
            *(uint4*)(xd + (kb2 * 64 + q2 * 16 + mm) * 8) = o;
        }
        __syncthreads();

        // GEMM2: out[16][128] = lrelu([x|df] @ W2 + u2_b + sc_b); wave owns 2 n-tiles
        {
            f32x4 acc20 = zacc, acc21 = zacc;
            #pragma unroll
            for (int kb = 0; kb < 4; ++kb) {
                bf16x8 a = *(const bf16x8*)(xd + (kb * 64 + lane) * 8);
                bf16x8 b0 = *(const bf16x8*)(packW2 + (size_t)(kb * 8 + wv * 2 + 0) * 512 + lane * 8);
                bf16x8 b1 = *(const bf16x8*)(packW2 + (size_t)(kb * 8 + wv * 2 + 1) * 512 + lane * 8);
                acc20 = __builtin_amdgcn_mfma_f32_16x16x32_bf16(a, b0, acc20, 0, 0, 0);
                acc21 = __builtin_amdgcn_mfma_f32_16x16x32_bf16(a, b1, acc21, 0, 0, 0);
            }
            #pragma unroll
            for (int t = 0; t < 2; ++t) {
                f32x4 ac = t ? acc21 : acc20;
                int colo = (wv * 2 + t) * 16 + nl;
                float bias = u2_b[colo] + sc_b[colo];
                #pragma unroll
                for (int r = 0; r < 4; ++r) {
                    int mm = quad * 4 + r;
                    out[(size_t)(p0 + mm) * COUT + colo] = lrelu(ac[r] + bias);
                }
            }
        }
    }
}

extern "C" void kernel_launch(void* const* d_in, const int* in_sizes, int n_in,
                              void* d_out, int out_size, void* d_ws, size_t ws_size,
                              hipStream_t stream) {
    const float* xyz   = (const float*)d_in[0];
    const float* df    = (const float*)d_in[1];
    const int*   nei   = (const int*)d_in[2];
    const float* pe_w1 = (const float*)d_in[3];
    const float* pe_b1 = (const float*)d_in[4];
    const float* pe_w2 = (const float*)d_in[5];
    const float* pe_b2 = (const float*)d_in[6];
    const float* u1_w  = (const float*)d_in[7];
    const float* u1_b  = (const float*)d_in[8];
    const float* wn_w1 = (const float*)d_in[9];
    const float* wn_b1 = (const float*)d_in[10];
    const float* wn_w2 = (const float*)d_in[11];
    const float* wn_b2 = (const float*)d_in[12];
    const float* wn_w3 = (const float*)d_in[13];
    const float* wn_b3 = (const float*)d_in[14];
    const float* lin_w = (const float*)d_in[15];
    const float* lin_b = (const float*)d_in[16];
    const float* u2_w  = (const float*)d_in[17];
    const float* u2_b  = (const float*)d_in[18];
    const float* sc_w  = (const float*)d_in[19];
    const float* sc_b  = (const float*)d_in[20];

    u32* feats2 = (u32*)d_ws;
    u16* packB  = (u16*)((char*)d_ws + WS_PACKB);
    u16* packW2 = (u16*)((char*)d_ws + WS_PACKW2);
    float* wnf  = (float*)((char*)d_ws + WS_WN);
    float* outp = (float*)d_out;
    float* locout = outp + (size_t)NPTS * COUT;

    hipLaunchKernelGGL(k_prep, dim3(NB_U1 + NB_PACK + NB_PACKW2 + 1), dim3(256), 0, stream,
                       df, u1_w, u1_b, feats2, lin_w, packB, u2_w, sc_w, packW2,
                       wn_w2, wn_b2, wn_w3, wn_b3, wnf);

    hipLaunchKernelGGL(k_fused, dim3(NPTS / 32), dim3(256), 0, stream,
                       xyz, nei, feats2,
                       pe_w1, pe_b1, pe_w2, pe_b2,
                       wn_w1, wn_b1, wnf,
                       packB, packW2, lin_b, u2_b, sc_b,
                       df, outp, locout);
}

// Round 9
// 221.903 us; speedup vs baseline: 1.4616x; 1.4616x over previous
//
#include <hip/hip_runtime.h>
#include <stdint.h>

#define NPTS 100000
#define KNEI 16
#define CIN 64
#define CMID 32
#define CONC 64
#define LINI 1024
#define COUT 128
#define APITCH 1032   // u16 per aggL row (keeps b128 16B alignment; spread verified)

typedef unsigned short u16;
typedef unsigned int u32;
typedef __attribute__((ext_vector_type(8))) short bf16x8;
typedef __attribute__((ext_vector_type(4))) float f32x4;

// ws layout (bytes):
//   [0, 6400000)            feats2: u32[N][16], channel-paired (c | c+16<<16)
//   [WS_PACKB, +131072)     packed lin_w bf16 (65536 elems, MFMA B-frag order)
//   [WS_PACKW2, +32768)     packed [u2_w; sc_w] bf16 (16384 elems, B-frag order)
//   [WS_WN, +576)           folded WeightNet: W23[8][16] fp32, b23[16] fp32
#define WS_PACKB  6400000
#define WS_PACKW2 (WS_PACKB + 131072)
#define WS_WN     (WS_PACKW2 + 32768)

#define NB_U1 1563            // 64 points per block (16/wave, MFMA path)
#define NB_PACK 256
#define NB_PACKW2 64

__device__ __forceinline__ float lrelu(float x) { return fmaxf(x, 0.1f * x); }

// exact RNE (one-time prep only)
__device__ __forceinline__ u32 f2bf(float f) {
    union { float f; u32 u; } v; v.f = f;
    return (v.u + 0x7FFFu + ((v.u >> 16) & 1u)) >> 16;
}
// fast round-half-up, scalar
__device__ __forceinline__ u16 f2bfF(float f) {
    union { float f; u32 u; } v; v.f = f;
    return (u16)((v.u + 0x8000u) >> 16);
}
// fast round-half-up, packed pair (low=a, high=b)
__device__ __forceinline__ u32 pkbf(float a, float b) {
    union { float f; u32 u; } x, y; x.f = a; y.f = b;
    return __builtin_amdgcn_perm(y.u + 0x8000u, x.u + 0x8000u, 0x07060302u);
}
__device__ __forceinline__ float bf2f(u32 h) {
    union { u32 u; float f; } v; v.u = h << 16; return v.f;
}

// ---- merged prep: u1 feats via MFMA (paired) + pack lin_w + pack W2 + fold WeightNet ----
__global__ __launch_bounds__(256) void k_prep(
    const float* __restrict__ df, const float* __restrict__ u1_w,
    const float* __restrict__ u1_b, u32* __restrict__ feats2,
    const float* __restrict__ lin_w, u16* __restrict__ packB,
    const float* __restrict__ u2_w, const float* __restrict__ sc_w,
    u16* __restrict__ packW2,
    const float* __restrict__ wn_w2, const float* __restrict__ wn_b2,
    const float* __restrict__ wn_w3, const float* __restrict__ wn_b3,
    float* __restrict__ wnf)
{
    int bid = blockIdx.x;
    if (bid < NB_U1) {
        // u1 GEMM: per wave, feats[16 pts][32 ch] = df[16][64] @ u1_w[64][32] + b.
        const int wv = threadIdx.x >> 6, lane = threadIdx.x & 63;
        const int quad = lane >> 4, nl = lane & 15;
        const int pbase = bid * 64 + wv * 16;
        if (pbase >= NPTS) return;

        bf16x8 bw[2][2];   // [nt][kk]
        #pragma unroll
        for (int nt = 0; nt < 2; ++nt)
            #pragma unroll
            for (int kk = 0; kk < 2; ++kk)
                #pragma unroll
                for (int j = 0; j < 8; ++j)
                    bw[nt][kk][j] = (short)f2bf(u1_w[(kk * 32 + quad * 8 + j) * CMID + nt * 16 + nl]);

        const float* arow = df + (size_t)(pbase + nl) * CIN + quad * 8;
        float4 a0 = *(const float4*)(arow + 0);
        float4 a1 = *(const float4*)(arow + 4);
        float4 a2 = *(const float4*)(arow + 32);
        float4 a3 = *(const float4*)(arow + 36);
        bf16x8 afr0, afr1;
        u32* ap0 = (u32*)&afr0; u32* ap1 = (u32*)&afr1;
        ap0[0] = pkbf(a0.x, a0.y); ap0[1] = pkbf(a0.z, a0.w);
        ap0[2] = pkbf(a1.x, a1.y); ap0[3] = pkbf(a1.z, a1.w);
        ap1[0] = pkbf(a2.x, a2.y); ap1[1] = pkbf(a2.z, a2.w);
        ap1[2] = pkbf(a3.x, a3.y); ap1[3] = pkbf(a3.z, a3.w);

        const f32x4 z = {0.f, 0.f, 0.f, 0.f};
        f32x4 acc0 = z, acc1 = z;
        acc0 = __builtin_amdgcn_mfma_f32_16x16x32_bf16(afr0, bw[0][0], acc0, 0, 0, 0);
        acc0 = __builtin_amdgcn_mfma_f32_16x16x32_bf16(afr1, bw[0][1], acc0, 0, 0, 0);
        acc1 = __builtin_amdgcn_mfma_f32_16x16x32_bf16(afr0, bw[1][0], acc1, 0, 0, 0);
        acc1 = __builtin_amdgcn_mfma_f32_16x16x32_bf16(afr1, bw[1][1], acc1, 0, 0, 0);

        float blo = u1_b[nl], bhi = u1_b[16 + nl];
        #pragma unroll
        for (int r = 0; r < 4; ++r) {
            int pt = pbase + quad * 4 + r;
            feats2[(size_t)pt * 16 + nl] = f2bf(acc0[r] + blo) | (f2bf(acc1[r] + bhi) << 16);
        }
    } else if (bid < NB_U1 + NB_PACK) {
        int t = (bid - NB_U1) * 256 + threadIdx.x;     // 65536 total
        int j = t & 7, ln = (t >> 3) & 63, s = t >> 9;
        int nt = s & 3, kb = s >> 2;
        int k = kb * 32 + (ln >> 4) * 8 + j;
        int n = nt * 16 + (ln & 15);
        packB[t] = (u16)f2bf(lin_w[k * 64 + n]);
    } else if (bid < NB_U1 + NB_PACK + NB_PACKW2) {
        int t = (bid - NB_U1 - NB_PACK) * 256 + threadIdx.x;   // 16384 total
        int j = t & 7, ln = (t >> 3) & 63, s = t >> 9;
        int nt2 = s & 7, kb2 = s >> 3;
        int k = kb2 * 32 + (ln >> 4) * 8 + j;
        int n = nt2 * 16 + (ln & 15);
        float v = (k < 64) ? u2_w[k * COUT + n] : sc_w[(k - 64) * COUT + n];
        packW2[t] = (u16)f2bf(v);
    } else {
        int t = threadIdx.x;
        if (t < 128) {
            int i = t >> 4, o = t & 15;
            float a = 0.f;
            #pragma unroll
            for (int m = 0; m < 8; ++m) a += wn_w2[i * 8 + m] * wn_w3[m * 16 + o];
            wnf[i * 16 + o] = a;
        } else if (t < 144) {
            int o = t - 128;
            float a = wn_b3[o];
            #pragma unroll
            for (int m = 0; m < 8; ++m) a += wn_b2[m] * wn_w3[m * 16 + o];
            wnf[128 + o] = a;
        }
    }
}

// ---- Fused: gather/PE/WN/einsum (phase 1) + GEMM1 + GEMM2 (phase 2). ----
// Block = 256 threads = 16 points; one wave handles 4 points in phase 1.
__global__ __launch_bounds__(256) void k_fused(
    const float* __restrict__ xyz, const int* __restrict__ nei,
    const u32* __restrict__ feats2,
    const float* __restrict__ pe_w1, const float* __restrict__ pe_b1,
    const float* __restrict__ pe_w2, const float* __restrict__ pe_b2,
    const float* __restrict__ wn_w1, const float* __restrict__ wn_b1,
    const float* __restrict__ wnf,
    const u16* __restrict__ packB, const u16* __restrict__ packW2,
    const float* __restrict__ lin_b,
    const float* __restrict__ u2_b, const float* __restrict__ sc_b,
    const float* __restrict__ df, float* __restrict__ out,
    float* __restrict__ locout)
{
    __shared__ __align__(16) u16 aggL[16 * APITCH];   // 33,024 B
    __shared__ float loc_s[4][4][16][3];              //  3,072 B (wave-private)
    __shared__ int   idx_s[4][4][16];                 //  1,024 B (wave-private)
    __shared__ __align__(16) u16 pexd[4][32][24];     //  6,144 B; pe in ph1, xd in ph2
    __shared__ __align__(16) u16 w_s[4][16][24];      //  3,072 B (wave-private)
    __shared__ __align__(16) u16 h1_s[4][4][16][8];   //  4,096 B bf16 h1 per (p,k)

    u16* xd = &pexd[0][0][0];                         // phase-2 alias (4 KB used)

    const int tid = threadIdx.x, wv = tid >> 6, lane = tid & 63;
    const int quad = lane >> 4, nl = lane & 15;
    const int p0 = blockIdx.x * 16;
    const int ptBase = p0 + wv * 4;

    // ---- phase 1, step 0: coords + indices + deduped h1 (lane: point=quad, k=nl) ----
    int pt0 = ptBase + quad;
    int idx0 = nei[pt0 * KNEI + nl];
    idx_s[wv][quad][nl] = idx0;
    {
        float cx = xyz[pt0 * 3 + 0], cy = xyz[pt0 * 3 + 1], cz = xyz[pt0 * 3 + 2];
        float lx0 = xyz[idx0 * 3 + 0] - cx;
        float ly0 = xyz[idx0 * 3 + 1] - cy;
        float lz0 = xyz[idx0 * 3 + 2] - cz;
        loc_s[wv][quad][nl][0] = lx0;
        loc_s[wv][quad][nl][1] = ly0;
        loc_s[wv][quad][nl][2] = lz0;
        float3 lv; lv.x = lx0; lv.y = ly0; lv.z = lz0;
        *(float3*)(locout + (size_t)(pt0 * KNEI + nl) * 3) = lv;
        // WeightNet layer-1 (only nonlinearity before the fold), bf16-packed
        uint4 hp;
        u32* hpp = (u32*)&hp;
        #pragma unroll
        for (int h = 0; h < 8; h += 2) {
            float a = lrelu(wn_b1[h]     + lx0 * wn_w1[h]     + ly0 * wn_w1[8 + h]     + lz0 * wn_w1[16 + h]);
            float b = lrelu(wn_b1[h + 1] + lx0 * wn_w1[h + 1] + ly0 * wn_w1[8 + h + 1] + lz0 * wn_w1[16 + h + 1]);
            hpp[h >> 1] = pkbf(a, b);
        }
        *(uint4*)&h1_s[wv][quad][nl][0] = hp;
    }

    // ---- preload per-lane weights ----
    float w1r0[8], w1r1[8], w1r2[8], b1v[8];
    #pragma unroll
    for (int j = 0; j < 8; ++j) {
        int h = quad * 8 + j;
        w1r0[j] = pe_w1[h]; w1r1[j] = pe_w1[32 + h]; w1r2[j] = pe_w1[64 + h];
        b1v[j] = pe_b1[h];
    }
    bf16x8 w2t[2];
    #pragma unroll
    for (int ct = 0; ct < 2; ++ct)
        #pragma unroll
        for (int j = 0; j < 8; ++j)
            w2t[ct][j] = (short)f2bf(pe_w2[(quad * 8 + j) * 32 + nl + 16 * ct]);
    float b2v[2][4];
    #pragma unroll
    for (int ct = 0; ct < 2; ++ct)
        #pragma unroll
        for (int r = 0; r < 4; ++r)
            b2v[ct][r] = pe_b2[16 * ct + quad * 4 + r];
    float wn3v[8][4], b23v[4];
    #pragma unroll
    for (int h = 0; h < 8; ++h)
        #pragma unroll
        for (int r = 0; r < 4; ++r)
            wn3v[h][r] = wnf[h * 16 + quad * 4 + r];
    #pragma unroll
    for (int r = 0; r < 4; ++r) b23v[r] = wnf[128 + quad * 4 + r];

    const f32x4 zacc = {0.f, 0.f, 0.f, 0.f};

    for (int p = 0; p < 4; ++p) {
        const int m = wv * 4 + p;   // block-local point row

        // ---- paired feats gather into B-frags via v_perm (quads 0,1; 2,3 zero) ----
        bf16x8 featf0 = 0, featf1 = 0;
        if (quad < 2) {
            u32 gv[8];
            #pragma unroll
            for (int j = 0; j < 8; ++j) {
                int idk = idx_s[wv][p][quad * 8 + j];
                gv[j] = feats2[(size_t)idk * 16 + nl];
            }
            u32* f0w = (u32*)&featf0;
            u32* f1w = (u32*)&featf1;
            #pragma unroll
            for (int jp = 0; jp < 4; ++jp) {
                u32 a = gv[2 * jp], b = gv[2 * jp + 1];
                f0w[jp] = __builtin_amdgcn_perm(b, a, 0x05040100u);   // lo16(a)|lo16(b)<<16
                f1w[jp] = __builtin_amdgcn_perm(b, a, 0x07060302u);   // hi16(a)|hi16(b)<<16
            }
        }

        float lx = loc_s[wv][p][nl][0];
        float ly = loc_s[wv][p][nl][1];
        float lz = loc_s[wv][p][nl][2];

        // ---- B1: ph in B-frag layout (h=quad*8+j, k_nei=nl) ----
        bf16x8 phf;
        {
            u32* ph32 = (u32*)&phf;
            #pragma unroll
            for (int j = 0; j < 8; j += 2) {
                float v0 = lrelu(b1v[j]     + lx * w1r0[j]     + ly * w1r1[j]     + lz * w1r2[j]);
                float v1 = lrelu(b1v[j + 1] + lx * w1r0[j + 1] + ly * w1r1[j + 1] + lz * w1r2[j + 1]);
                ph32[j >> 1] = pkbf(v0, v1);
            }
        }

        // ---- B2: pe^T = w2^T @ ph : 2 MFMAs ----
        f32x4 pe0 = __builtin_amdgcn_mfma_f32_16x16x32_bf16(w2t[0], phf, zacc, 0, 0, 0);
        f32x4 pe1 = __builtin_amdgcn_mfma_f32_16x16x32_bf16(w2t[1], phf, zacc, 0, 0, 0);

        #pragma unroll
        for (int r = 0; r < 4; ++r) {
            pexd[wv][quad * 4 + r][nl]      = f2bfF(lrelu(pe0[r] + b2v[0][r]));
            pexd[wv][16 + quad * 4 + r][nl] = f2bfF(lrelu(pe1[r] + b2v[1][r]));
        }

        // ---- folded WeightNet output (h1 from LDS broadcast, W23 in regs) ----
        {
            uint4 hv = *(const uint4*)&h1_s[wv][p][nl][0];
            float h1f[8];
            h1f[0] = bf2f(hv.x & 0xffffu); h1f[1] = bf2f(hv.x >> 16);
            h1f[2] = bf2f(hv.y & 0xffffu); h1f[3] = bf2f(hv.y >> 16);
            h1f[4] = bf2f(hv.z & 0xffffu); h1f[5] = bf2f(hv.z >> 16);
            h1f[6] = bf2f(hv.w & 0xffffu); h1f[7] = bf2f(hv.w >> 16);
            #pragma unroll
            for (int r = 0; r < 4; ++r) {
                float a = b23v[r];
                #pragma unroll
                for (int h = 0; h < 8; ++h) a += h1f[h] * wn3v[h][r];
                w_s[wv][quad * 4 + r][nl] = f2bfF(lrelu(a));
            }
        }
        // wave-private LDS: intra-wave ordering via lgkmcnt; no block barrier.

        // ---- read frags: wA (A: o=nl, k=quad*8+j), peB (B: k, c=nl) ----
        bf16x8 wA = 0, peB0 = 0, peB1 = 0;
        if (quad < 2) {
            wA   = *(const bf16x8*)&w_s[wv][nl][quad * 8];
            peB0 = *(const bf16x8*)&pexd[wv][nl][quad * 8];
            peB1 = *(const bf16x8*)&pexd[wv][nl + 16][quad * 8];
        }

        // ---- einsum: D[o][c] = w^T @ nf, 4 c-tiles, K=16 (padded) ----
        f32x4 c0a = __builtin_amdgcn_mfma_f32_16x16x32_bf16(wA, featf0, zacc, 0, 0, 0);
        f32x4 c1a = __builtin_amdgcn_mfma_f32_16x16x32_bf16(wA, featf1, zacc, 0, 0, 0);
        f32x4 c2a = __builtin_amdgcn_mfma_f32_16x16x32_bf16(wA, peB0, zacc, 0, 0, 0);
        f32x4 c3a = __builtin_amdgcn_mfma_f32_16x16x32_bf16(wA, peB1, zacc, 0, 0, 0);

        // ---- store agg row into LDS (plain layout, pitch 1032) ----
        {
            u16* arow = aggL + m * APITCH;
            f32x4 cc[4] = {c0a, c1a, c2a, c3a};
            #pragma unroll
            for (int ct = 0; ct < 4; ++ct) {
                int e = (nl + 16 * ct) * 16 + quad * 4;
                uint2 o;
                o.x = pkbf(cc[ct][0], cc[ct][1]);
                o.y = pkbf(cc[ct][2], cc[ct][3]);
                *(uint2*)(arow + e) = o;
            }
        }
    }
    __syncthreads();   // all aggL rows visible; pe region now dead -> xd

    // ================= phase 2 =================
    // GEMM1: x[16][64] = lrelu(agg @ lin_w + lin_b); wave wv owns n-tile nt=wv.
    const int nt = wv;
    {
        const u16* bp = packB + nt * 512 + lane * 8;
        const u16* arow = aggL + nl * APITCH;
        f32x4 accA = zacc, accB = zacc;
        #pragma unroll
        for (int kk = 0; kk < 16; ++kk) {
            int kbA = 2 * kk, kbB = 2 * kk + 1;
            bf16x8 aA = *(const bf16x8*)(arow + (4 * kbA + quad) * 8);
            bf16x8 aB = *(const bf16x8*)(arow + (4 * kbB + quad) * 8);
            bf16x8 bA = *(const bf16x8*)(bp + kbA * 2048);
            bf16x8 bB = *(const bf16x8*)(bp + kbB * 2048);
            accA = __builtin_amdgcn_mfma_f32_16x16x32_bf16(aA, bA, accA, 0, 0, 0);
            accB = __builtin_amdgcn_mfma_f32_16x16x32_bf16(aB, bB, accB, 0, 0, 0);
        }
        int col = nt * 16 + nl;
        float lb = lin_b[col];
        int kb2 = col >> 5, q2 = (col >> 3) & 3, j2 = col & 7;
        #pragma unroll
        for (int r = 0; r < 4; ++r) {
            int mm = quad * 4 + r;
            float v = lrelu(accA[r] + accB[r] + lb);
            xd[(kb2 * 64 + q2 * 16 + mm) * 8 + j2] = f2bfF(v);
        }
    }
    // df -> xd (cols 64..127)
    if (tid < 128) {
        int mm = tid >> 3, cg = tid & 7;
        int colk = 64 + cg * 8;
        const float* dfr = df + (size_t)(p0 + mm) * CIN + cg * 8;
        float4 f0 = *(const float4*)(dfr);
        float4 f1 = *(const float4*)(dfr + 4);
        int kb2 = colk >> 5, q2 = (colk >> 3) & 3;
        uint4 o;
        o.x = pkbf(f0.x, f0.y);
        o.y = pkbf(f0.z, f0.w);
        o.z = pkbf(f1.x, f1.y);
        o.w = pkbf(f1.z, f1.w);
        *(uint4*)(xd + (kb2 * 64 + q2 * 16 + mm) * 8) = o;
    }
    __syncthreads();

    // GEMM2: out[16][128] = lrelu([x|df] @ W2 + u2_b + sc_b); wave owns 2 n-tiles
    {
        f32x4 acc20 = zacc, acc21 = zacc;
        #pragma unroll
        for (int kb = 0; kb < 4; ++kb) {
            bf16x8 a = *(const bf16x8*)(xd + (kb * 64 + lane) * 8);
            bf16x8 b0 = *(const bf16x8*)(packW2 + (size_t)(kb * 8 + wv * 2 + 0) * 512 + lane * 8);
            bf16x8 b1 = *(const bf16x8*)(packW2 + (size_t)(kb * 8 + wv * 2 + 1) * 512 + lane * 8);
            acc20 = __builtin_amdgcn_mfma_f32_16x16x32_bf16(a, b0, acc20, 0, 0, 0);
            acc21 = __builtin_amdgcn_mfma_f32_16x16x32_bf16(a, b1, acc21, 0, 0, 0);
        }
        #pragma unroll
        for (int t = 0; t < 2; ++t) {
            f32x4 ac = t ? acc21 : acc20;
            int colo = (wv * 2 + t) * 16 + nl;
            float bias = u2_b[colo] + sc_b[colo];
            #pragma unroll
            for (int r = 0; r < 4; ++r) {
                int mm = quad * 4 + r;
                out[(size_t)(p0 + mm) * COUT + colo] = lrelu(ac[r] + bias);
            }
        }
    }
}

extern "C" void kernel_launch(void* const* d_in, const int* in_sizes, int n_in,
                              void* d_out, int out_size, void* d_ws, size_t ws_size,
                              hipStream_t stream) {
    const float* xyz   = (const float*)d_in[0];
    const float* df    = (const float*)d_in[1];
    const int*   nei   = (const int*)d_in[2];
    const float* pe_w1 = (const float*)d_in[3];
    const float* pe_b1 = (const float*)d_in[4];
    const float* pe_w2 = (const float*)d_in[5];
    const float* pe_b2 = (const float*)d_in[6];
    const float* u1_w  = (const float*)d_in[7];
    const float* u1_b  = (const float*)d_in[8];
    const float* wn_w1 = (const float*)d_in[9];
    const float* wn_b1 = (const float*)d_in[10];
    const float* wn_w2 = (const float*)d_in[11];
    const float* wn_b2 = (const float*)d_in[12];
    const float* wn_w3 = (const float*)d_in[13];
    const float* wn_b3 = (const float*)d_in[14];
    const float* lin_w = (const float*)d_in[15];
    const float* lin_b = (const float*)d_in[16];
    const float* u2_w  = (const float*)d_in[17];
    const float* u2_b  = (const float*)d_in[18];
    const float* sc_w  = (const float*)d_in[19];
    const float* sc_b  = (const float*)d_in[20];

    u32* feats2 = (u32*)d_ws;
    u16* packB  = (u16*)((char*)d_ws + WS_PACKB);
    u16* packW2 = (u16*)((char*)d_ws + WS_PACKW2);
    float* wnf  = (float*)((char*)d_ws + WS_WN);
    float* outp = (float*)d_out;
    float* locout = outp + (size_t)NPTS * COUT;

    hipLaunchKernelGGL(k_prep, dim3(NB_U1 + NB_PACK + NB_PACKW2 + 1), dim3(256), 0, stream,
                       df, u1_w, u1_b, feats2, lin_w, packB, u2_w, sc_w, packW2,
                       wn_w2, wn_b2, wn_w3, wn_b3, wnf);

    hipLaunchKernelGGL(k_fused, dim3(NPTS / 16), dim3(256), 0, stream,
                       xyz, nei, feats2,
                       pe_w1, pe_b1, pe_w2, pe_b2,
                       wn_w1, wn_b1, wnf,
                       packB, packW2, lin_b, u2_b, sc_b,
                       df, outp, locout);
}

// Round 10
// 213.085 us; speedup vs baseline: 1.5221x; 1.0414x over previous
//
#include <hip/hip_runtime.h>
#include <stdint.h>

#define NPTS 100000
#define KNEI 16
#define CIN 64
#define CMID 32
#define CONC 64
#define LINI 1024
#define COUT 128
#define APITCH 1032   // u16 per aggL row (keeps b128 16B alignment; spread verified)

typedef unsigned short u16;
typedef unsigned int u32;
typedef __attribute__((ext_vector_type(8))) short bf16x8;
typedef __attribute__((ext_vector_type(4))) float f32x4;

// ws layout (bytes):
//   [0, 6400000)            feats2: u32[N][16], channel-paired (c | c+16<<16)
//   [WS_PACKB, +131072)     packed lin_w bf16 (65536 elems, MFMA B-frag order)
//   [WS_PACKW2, +32768)     packed [u2_w; sc_w] bf16 (16384 elems, B-frag order)
//   [WS_WN, +576)           folded WeightNet: W23[8][16] fp32, b23[16] fp32
#define WS_PACKB  6400000
#define WS_PACKW2 (WS_PACKB + 131072)
#define WS_WN     (WS_PACKW2 + 32768)

#define NB_U1 1563            // 64 points per block (16/wave, MFMA path)
#define NB_PACK 256
#define NB_PACKW2 64

__device__ __forceinline__ float lrelu(float x) { return fmaxf(x, 0.1f * x); }

// exact RNE (one-time prep only)
__device__ __forceinline__ u32 f2bf(float f) {
    union { float f; u32 u; } v; v.f = f;
    return (v.u + 0x7FFFu + ((v.u >> 16) & 1u)) >> 16;
}
// fast round-half-up, scalar
__device__ __forceinline__ u16 f2bfF(float f) {
    union { float f; u32 u; } v; v.f = f;
    return (u16)((v.u + 0x8000u) >> 16);
}
// fast round-half-up, packed pair (low=a, high=b)
__device__ __forceinline__ u32 pkbf(float a, float b) {
    union { float f; u32 u; } x, y; x.f = a; y.f = b;
    return __builtin_amdgcn_perm(y.u + 0x8000u, x.u + 0x8000u, 0x07060302u);
}
__device__ __forceinline__ float bf2f(u32 h) {
    union { u32 u; float f; } v; v.u = h << 16; return v.f;
}

// ---- merged prep: u1 feats via MFMA (paired) + pack lin_w + pack W2 + fold WeightNet ----
__global__ __launch_bounds__(256) void k_prep(
    const float* __restrict__ df, const float* __restrict__ u1_w,
    const float* __restrict__ u1_b, u32* __restrict__ feats2,
    const float* __restrict__ lin_w, u16* __restrict__ packB,
    const float* __restrict__ u2_w, const float* __restrict__ sc_w,
    u16* __restrict__ packW2,
    const float* __restrict__ wn_w2, const float* __restrict__ wn_b2,
    const float* __restrict__ wn_w3, const float* __restrict__ wn_b3,
    float* __restrict__ wnf)
{
    int bid = blockIdx.x;
    if (bid < NB_U1) {
        // u1 GEMM: per wave, feats[16 pts][32 ch] = df[16][64] @ u1_w[64][32] + b.
        const int wv = threadIdx.x >> 6, lane = threadIdx.x & 63;
        const int quad = lane >> 4, nl = lane & 15;
        const int pbase = bid * 64 + wv * 16;
        if (pbase >= NPTS) return;

        bf16x8 bw[2][2];   // [nt][kk]
        #pragma unroll
        for (int nt = 0; nt < 2; ++nt)
            #pragma unroll
            for (int kk = 0; kk < 2; ++kk)
                #pragma unroll
                for (int j = 0; j < 8; ++j)
                    bw[nt][kk][j] = (short)f2bf(u1_w[(kk * 32 + quad * 8 + j) * CMID + nt * 16 + nl]);

        const float* arow = df + (size_t)(pbase + nl) * CIN + quad * 8;
        float4 a0 = *(const float4*)(arow + 0);
        float4 a1 = *(const float4*)(arow + 4);
        float4 a2 = *(const float4*)(arow + 32);
        float4 a3 = *(const float4*)(arow + 36);
        bf16x8 afr0, afr1;
        u32* ap0 = (u32*)&afr0; u32* ap1 = (u32*)&afr1;
        ap0[0] = pkbf(a0.x, a0.y); ap0[1] = pkbf(a0.z, a0.w);
        ap0[2] = pkbf(a1.x, a1.y); ap0[3] = pkbf(a1.z, a1.w);
        ap1[0] = pkbf(a2.x, a2.y); ap1[1] = pkbf(a2.z, a2.w);
        ap1[2] = pkbf(a3.x, a3.y); ap1[3] = pkbf(a3.z, a3.w);

        const f32x4 z = {0.f, 0.f, 0.f, 0.f};
        f32x4 acc0 = z, acc1 = z;
        acc0 = __builtin_amdgcn_mfma_f32_16x16x32_bf16(afr0, bw[0][0], acc0, 0, 0, 0);
        acc0 = __builtin_amdgcn_mfma_f32_16x16x32_bf16(afr1, bw[0][1], acc0, 0, 0, 0);
        acc1 = __builtin_amdgcn_mfma_f32_16x16x32_bf16(afr0, bw[1][0], acc1, 0, 0, 0);
        acc1 = __builtin_amdgcn_mfma_f32_16x16x32_bf16(afr1, bw[1][1], acc1, 0, 0, 0);

        float blo = u1_b[nl], bhi = u1_b[16 + nl];
        #pragma unroll
        for (int r = 0; r < 4; ++r) {
            int pt = pbase + quad * 4 + r;
            feats2[(size_t)pt * 16 + nl] = f2bf(acc0[r] + blo) | (f2bf(acc1[r] + bhi) << 16);
        }
    } else if (bid < NB_U1 + NB_PACK) {
        int t = (bid - NB_U1) * 256 + threadIdx.x;     // 65536 total
        int j = t & 7, ln = (t >> 3) & 63, s = t >> 9;
        int nt = s & 3, kb = s >> 2;
        int k = kb * 32 + (ln >> 4) * 8 + j;
        int n = nt * 16 + (ln & 15);
        packB[t] = (u16)f2bf(lin_w[k * 64 + n]);
    } else if (bid < NB_U1 + NB_PACK + NB_PACKW2) {
        int t = (bid - NB_U1 - NB_PACK) * 256 + threadIdx.x;   // 16384 total
        int j = t & 7, ln = (t >> 3) & 63, s = t >> 9;
        int nt2 = s & 7, kb2 = s >> 3;
        int k = kb2 * 32 + (ln >> 4) * 8 + j;
        int n = nt2 * 16 + (ln & 15);
        float v = (k < 64) ? u2_w[k * COUT + n] : sc_w[(k - 64) * COUT + n];
        packW2[t] = (u16)f2bf(v);
    } else {
        int t = threadIdx.x;
        if (t < 128) {
            int i = t >> 4, o = t & 15;
            float a = 0.f;
            #pragma unroll
            for (int m = 0; m < 8; ++m) a += wn_w2[i * 8 + m] * wn_w3[m * 16 + o];
            wnf[i * 16 + o] = a;
        } else if (t < 144) {
            int o = t - 128;
            float a = wn_b3[o];
            #pragma unroll
            for (int m = 0; m < 8; ++m) a += wn_b2[m] * wn_w3[m * 16 + o];
            wnf[128 + o] = a;
        }
    }
}

// ---- Fused: gather/PE/WN/einsum (phase 1) + GEMM1 + GEMM2 (phase 2). ----
// Block = 256 threads = 16 points; one wave handles 4 points in phase 1.
// LDS slimmed to 40,192 B (4 blocks/CU): loc/h1 live in registers, moved
// cross-lane per-p via ds_bpermute; WeightNet fold is one MFMA (bias in C).
__global__ __launch_bounds__(256) void k_fused(
    const float* __restrict__ xyz, const int* __restrict__ nei,
    const u32* __restrict__ feats2,
    const float* __restrict__ pe_w1, const float* __restrict__ pe_b1,
    const float* __restrict__ pe_w2, const float* __restrict__ pe_b2,
    const float* __restrict__ wn_w1, const float* __restrict__ wn_b1,
    const float* __restrict__ wnf,
    const u16* __restrict__ packB, const u16* __restrict__ packW2,
    const float* __restrict__ lin_b,
    const float* __restrict__ u2_b, const float* __restrict__ sc_b,
    const float* __restrict__ df, float* __restrict__ out,
    float* __restrict__ locout)
{
    __shared__ __align__(16) u16 aggL[16 * APITCH];   // 33,024 B
    __shared__ int   idx_s[4][4][16];                 //  1,024 B (wave-private)
    __shared__ __align__(16) u16 pexd[4][32][16];     //  4,096 B; pe in ph1, xd in ph2
    __shared__ __align__(16) u16 w_s[4][16][16];      //  2,048 B (wave-private)

    u16* xd = &pexd[0][0][0];                         // phase-2 alias (4 KB, exact)

    const int tid = threadIdx.x, wv = tid >> 6, lane = tid & 63;
    const int quad = lane >> 4, nl = lane & 15;
    const int p0 = blockIdx.x * 16;
    const int ptBase = p0 + wv * 4;

    // ---- phase 1, step 0: coords + indices + h1 (lane: point=quad, k=nl) ----
    // loc and h1 stay in REGISTERS; consumers fetch them per-p via ds_bpermute.
    int pt0 = ptBase + quad;
    int idx0 = nei[pt0 * KNEI + nl];
    idx_s[wv][quad][nl] = idx0;
    float lx0, ly0, lz0;
    uint4 hp;
    {
        float cx = xyz[pt0 * 3 + 0], cy = xyz[pt0 * 3 + 1], cz = xyz[pt0 * 3 + 2];
        lx0 = xyz[idx0 * 3 + 0] - cx;
        ly0 = xyz[idx0 * 3 + 1] - cy;
        lz0 = xyz[idx0 * 3 + 2] - cz;
        float3 lv; lv.x = lx0; lv.y = ly0; lv.z = lz0;
        *(float3*)(locout + (size_t)(pt0 * KNEI + nl) * 3) = lv;
        // WeightNet layer-1 (only nonlinearity before the fold), bf16-packed
        u32* hpp = (u32*)&hp;
        #pragma unroll
        for (int h = 0; h < 8; h += 2) {
            float a = lrelu(wn_b1[h]     + lx0 * wn_w1[h]     + ly0 * wn_w1[8 + h]     + lz0 * wn_w1[16 + h]);
            float b = lrelu(wn_b1[h + 1] + lx0 * wn_w1[h + 1] + ly0 * wn_w1[8 + h + 1] + lz0 * wn_w1[16 + h + 1]);
            hpp[h >> 1] = pkbf(a, b);
        }
    }

    // ---- preload per-lane weights ----
    float w1r0[8], w1r1[8], w1r2[8], b1v[8];
    #pragma unroll
    for (int j = 0; j < 8; ++j) {
        int h = quad * 8 + j;
        w1r0[j] = pe_w1[h]; w1r1[j] = pe_w1[32 + h]; w1r2[j] = pe_w1[64 + h];
        b1v[j] = pe_b1[h];
    }
    bf16x8 w2t[2];
    #pragma unroll
    for (int ct = 0; ct < 2; ++ct)
        #pragma unroll
        for (int j = 0; j < 8; ++j)
            w2t[ct][j] = (short)f2bf(pe_w2[(quad * 8 + j) * 32 + nl + 16 * ct]);
    f32x4 b2c[2];                       // pe_b2 rides the MFMA C operand
    #pragma unroll
    for (int ct = 0; ct < 2; ++ct)
        #pragma unroll
        for (int r = 0; r < 4; ++r)
            b2c[ct][r] = pe_b2[16 * ct + quad * 4 + r];
    // folded-WeightNet A-frag: A[o=nl][h=j] = wnf[j][o], quad0 only (h<8)
    bf16x8 wnfA = 0;
    if (quad == 0) {
        #pragma unroll
        for (int j = 0; j < 8; ++j)
            wnfA[j] = (short)f2bf(wnf[j * 16 + nl]);
    }
    f32x4 b23c;                         // fold bias rides the MFMA C operand
    #pragma unroll
    for (int r = 0; r < 4; ++r) b23c[r] = wnf[128 + quad * 4 + r];

    const f32x4 zacc = {0.f, 0.f, 0.f, 0.f};

    for (int p = 0; p < 4; ++p) {
        const int m = wv * 4 + p;   // block-local point row
        const int pidx = (p * 16 + nl) << 2;   // bpermute byte index: source lane p*16+nl

        // ---- paired feats gather into B-frags via v_perm (quads 0,1; 2,3 zero) ----
        bf16x8 featf0 = 0, featf1 = 0;
        if (quad < 2) {
            u32 gv[8];
            #pragma unroll
            for (int j = 0; j < 8; ++j) {
                int idk = idx_s[wv][p][quad * 8 + j];
                gv[j] = feats2[(size_t)idk * 16 + nl];
            }
            u32* f0w = (u32*)&featf0;
            u32* f1w = (u32*)&featf1;
            #pragma unroll
            for (int jp = 0; jp < 4; ++jp) {
                u32 a = gv[2 * jp], b = gv[2 * jp + 1];
                f0w[jp] = __builtin_amdgcn_perm(b, a, 0x05040100u);   // lo16(a)|lo16(b)<<16
                f1w[jp] = __builtin_amdgcn_perm(b, a, 0x07060302u);   // hi16(a)|hi16(b)<<16
            }
        }

        // ---- loc for (point p, k=nl) pulled cross-lane (all lanes active) ----
        float lx = __int_as_float(__builtin_amdgcn_ds_bpermute(pidx, __float_as_int(lx0)));
        float ly = __int_as_float(__builtin_amdgcn_ds_bpermute(pidx, __float_as_int(ly0)));
        float lz = __int_as_float(__builtin_amdgcn_ds_bpermute(pidx, __float_as_int(lz0)));

        // ---- h1 B-frag: B[h=quad*8+j][k=nl] = h1[p][nl][j]; quads 1-3 zero ----
        u32 hb0 = (u32)__builtin_amdgcn_ds_bpermute(pidx, (int)hp.x);
        u32 hb1 = (u32)__builtin_amdgcn_ds_bpermute(pidx, (int)hp.y);
        u32 hb2 = (u32)__builtin_amdgcn_ds_bpermute(pidx, (int)hp.z);
        u32 hb3 = (u32)__builtin_amdgcn_ds_bpermute(pidx, (int)hp.w);
        bf16x8 h1B = 0;
        if (quad == 0) {
            u32* hb = (u32*)&h1B;
            hb[0] = hb0; hb[1] = hb1; hb[2] = hb2; hb[3] = hb3;
        }

        // ---- B1: ph in B-frag layout (h=quad*8+j, k_nei=nl) ----
        bf16x8 phf;
        {
            u32* ph32 = (u32*)&phf;
            #pragma unroll
            for (int j = 0; j < 8; j += 2) {
                float v0 = lrelu(b1v[j]     + lx * w1r0[j]     + ly * w1r1[j]     + lz * w1r2[j]);
                float v1 = lrelu(b1v[j + 1] + lx * w1r0[j + 1] + ly * w1r1[j + 1] + lz * w1r2[j + 1]);
                ph32[j >> 1] = pkbf(v0, v1);
            }
        }

        // ---- B2: pe^T = w2^T @ ph + b2 : 2 MFMAs (bias in C) ----
        f32x4 pe0 = __builtin_amdgcn_mfma_f32_16x16x32_bf16(w2t[0], phf, b2c[0], 0, 0, 0);
        f32x4 pe1 = __builtin_amdgcn_mfma_f32_16x16x32_bf16(w2t[1], phf, b2c[1], 0, 0, 0);

        #pragma unroll
        for (int r = 0; r < 4; ++r) {
            pexd[wv][quad * 4 + r][nl]      = f2bfF(lrelu(pe0[r]));
            pexd[wv][16 + quad * 4 + r][nl] = f2bfF(lrelu(pe1[r]));
        }

        // ---- folded WeightNet via MFMA: w[o][k] = lrelu(wnf^T @ h1 + b23) ----
        {
            f32x4 wacc = __builtin_amdgcn_mfma_f32_16x16x32_bf16(wnfA, h1B, b23c, 0, 0, 0);
            #pragma unroll
            for (int r = 0; r < 4; ++r)
                w_s[wv][quad * 4 + r][nl] = f2bfF(lrelu(wacc[r]));
        }
        // wave-private LDS: intra-wave ordering via lgkmcnt; no block barrier.

        // ---- read frags: wA (A: o=nl, k=quad*8+j), peB (B: k, c=nl) ----
        bf16x8 wA = 0, peB0 = 0, peB1 = 0;
        if (quad < 2) {
            wA   = *(const bf16x8*)&w_s[wv][nl][quad * 8];
            peB0 = *(const bf16x8*)&pexd[wv][nl][quad * 8];
            peB1 = *(const bf16x8*)&pexd[wv][nl + 16][quad * 8];
        }

        // ---- einsum: D[o][c] = w^T @ nf, 4 c-tiles, K=16 (padded) ----
        f32x4 c0a = __builtin_amdgcn_mfma_f32_16x16x32_bf16(wA, featf0, zacc, 0, 0, 0);
        f32x4 c1a = __builtin_amdgcn_mfma_f32_16x16x32_bf16(wA, featf1, zacc, 0, 0, 0);
        f32x4 c2a = __builtin_amdgcn_mfma_f32_16x16x32_bf16(wA, peB0, zacc, 0, 0, 0);
        f32x4 c3a = __builtin_amdgcn_mfma_f32_16x16x32_bf16(wA, peB1, zacc, 0, 0, 0);

        // ---- store agg row into LDS (plain layout, pitch 1032) ----
        {
            u16* arow = aggL + m * APITCH;
            f32x4 cc[4] = {c0a, c1a, c2a, c3a};
            #pragma unroll
            for (int ct = 0; ct < 4; ++ct) {
                int e = (nl + 16 * ct) * 16 + quad * 4;
                uint2 o;
                o.x = pkbf(cc[ct][0], cc[ct][1]);
                o.y = pkbf(cc[ct][2], cc[ct][3]);
                *(uint2*)(arow + e) = o;
            }
        }
    }
    __syncthreads();   // all aggL rows visible; pe region now dead -> xd

    // ================= phase 2 =================
    // GEMM1: x[16][64] = lrelu(agg @ lin_w + lin_b); wave wv owns n-tile nt=wv.
    const int nt = wv;
    {
        const u16* bp = packB + nt * 512 + lane * 8;
        const u16* arow = aggL + nl * APITCH;
        f32x4 accA = zacc, accB = zacc;
        #pragma unroll
        for (int kk = 0; kk < 16; ++kk) {
            int kbA = 2 * kk, kbB = 2 * kk + 1;
            bf16x8 aA = *(const bf16x8*)(arow + (4 * kbA + quad) * 8);
            bf16x8 aB = *(const bf16x8*)(arow + (4 * kbB + quad) * 8);
            bf16x8 bA = *(const bf16x8*)(bp + kbA * 2048);
            bf16x8 bB = *(const bf16x8*)(bp + kbB * 2048);
            accA = __builtin_amdgcn_mfma_f32_16x16x32_bf16(aA, bA, accA, 0, 0, 0);
            accB = __builtin_amdgcn_mfma_f32_16x16x32_bf16(aB, bB, accB, 0, 0, 0);
        }
        int col = nt * 16 + nl;
        float lb = lin_b[col];
        int kb2 = col >> 5, q2 = (col >> 3) & 3, j2 = col & 7;
        #pragma unroll
        for (int r = 0; r < 4; ++r) {
            int mm = quad * 4 + r;
            float v = lrelu(accA[r] + accB[r] + lb);
            xd[(kb2 * 64 + q2 * 16 + mm) * 8 + j2] = f2bfF(v);
        }
    }
    // df -> xd (cols 64..127)
    if (tid < 128) {
        int mm = tid >> 3, cg = tid & 7;
        int colk = 64 + cg * 8;
        const float* dfr = df + (size_t)(p0 + mm) * CIN + cg * 8;
        float4 f0 = *(const float4*)(dfr);
        float4 f1 = *(const float4*)(dfr + 4);
        int kb2 = colk >> 5, q2 = (colk >> 3) & 3;
        uint4 o;
        o.x = pkbf(f0.x, f0.y);
        o.y = pkbf(f0.z, f0.w);
        o.z = pkbf(f1.x, f1.y);
        o.w = pkbf(f1.z, f1.w);
        *(uint4*)(xd + (kb2 * 64 + q2 * 16 + mm) * 8) = o;
    }
    __syncthreads();

    // GEMM2: out[16][128] = lrelu([x|df] @ W2 + u2_b + sc_b); wave owns 2 n-tiles
    {
        f32x4 acc20 = zacc, acc21 = zacc;
        #pragma unroll
        for (int kb = 0; kb < 4; ++kb) {
            bf16x8 a = *(const bf16x8*)(xd + (kb * 64 + lane) * 8);
            bf16x8 b0 = *(const bf16x8*)(packW2 + (size_t)(kb * 8 + wv * 2 + 0) * 512 + lane * 8);
            bf16x8 b1 = *(const bf16x8*)(packW2 + (size_t)(kb * 8 + wv * 2 + 1) * 512 + lane * 8);
            acc20 = __builtin_amdgcn_mfma_f32_16x16x32_bf16(a, b0, acc20, 0, 0, 0);
            acc21 = __builtin_amdgcn_mfma_f32_16x16x32_bf16(a, b1, acc21, 0, 0, 0);
        }
        #pragma unroll
        for (int t = 0; t < 2; ++t) {
            f32x4 ac = t ? acc21 : acc20;
            int colo = (wv * 2 + t) * 16 + nl;
            float bias = u2_b[colo] + sc_b[colo];
            #pragma unroll
            for (int r = 0; r < 4; ++r) {
                int mm = quad * 4 + r;
                out[(size_t)(p0 + mm) * COUT + colo] = lrelu(ac[r] + bias);
            }
        }
    }
}

extern "C" void kernel_launch(void* const* d_in, const int* in_sizes, int n_in,
                              void* d_out, int out_size, void* d_ws, size_t ws_size,
                              hipStream_t stream) {
    const float* xyz   = (const float*)d_in[0];
    const float* df    = (const float*)d_in[1];
    const int*   nei   = (const int*)d_in[2];
    const float* pe_w1 = (const float*)d_in[3];
    const float* pe_b1 = (const float*)d_in[4];
    const float* pe_w2 = (const float*)d_in[5];
    const float* pe_b2 = (const float*)d_in[6];
    const float* u1_w  = (const float*)d_in[7];
    const float* u1_b  = (const float*)d_in[8];
    const float* wn_w1 = (const float*)d_in[9];
    const float* wn_b1 = (const float*)d_in[10];
    const float* wn_w2 = (const float*)d_in[11];
    const float* wn_b2 = (const float*)d_in[12];
    const float* wn_w3 = (const float*)d_in[13];
    const float* wn_b3 = (const float*)d_in[14];
    const float* lin_w = (const float*)d_in[15];
    const float* lin_b = (const float*)d_in[16];
    const float* u2_w  = (const float*)d_in[17];
    const float* u2_b  = (const float*)d_in[18];
    const float* sc_w  = (const float*)d_in[19];
    const float* sc_b  = (const float*)d_in[20];

    u32* feats2 = (u32*)d_ws;
    u16* packB  = (u16*)((char*)d_ws + WS_PACKB);
    u16* packW2 = (u16*)((char*)d_ws + WS_PACKW2);
    float* wnf  = (float*)((char*)d_ws + WS_WN);
    float* outp = (float*)d_out;
    float* locout = outp + (size_t)NPTS * COUT;

    hipLaunchKernelGGL(k_prep, dim3(NB_U1 + NB_PACK + NB_PACKW2 + 1), dim3(256), 0, stream,
                       df, u1_w, u1_b, feats2, lin_w, packB, u2_w, sc_w, packW2,
                       wn_w2, wn_b2, wn_w3, wn_b3, wnf);

    hipLaunchKernelGGL(k_fused, dim3(NPTS / 16), dim3(256), 0, stream,
                       xyz, nei, feats2,
                       pe_w1, pe_b1, pe_w2, pe_b2,
                       wn_w1, wn_b1, wnf,
                       packB, packW2, lin_b, u2_b, sc_b,
                       df, outp, locout);
}

// Round 11
// 206.494 us; speedup vs baseline: 1.5707x; 1.0319x over previous
//
#include <hip/hip_runtime.h>
#include <stdint.h>

#define NPTS 100000
#define KNEI 16
#define CIN 64
#define CMID 32
#define CONC 64
#define LINI 1024
#define COUT 128
#define APITCH 1032   // u16 per aggL row (keeps b128 16B alignment; spread verified)

typedef unsigned short u16;
typedef unsigned int u32;
typedef __attribute__((ext_vector_type(8))) short bf16x8;
typedef __attribute__((ext_vector_type(4))) float f32x4;

// ws layout (bytes):
//   [0, 6400000)            feats2: u32[N][16], channel-paired (c | c+16<<16)
//   [WS_PACKB, +131072)     packed lin_w bf16 (65536 elems, MFMA B-frag order)
//   [WS_PACKW2, +32768)     packed [u2_w; sc_w] bf16 (16384 elems, B-frag order)
//   [WS_WN, +576)           folded WeightNet: W23[8][16] fp32, b23[16] fp32
//   [WS_PW2, +2048)         packed pe_w2 bf16, B2 A-frag order (1024 elems)
//   [WS_WNP, +256)          packed W23^T bf16, fold A-frag order (128 elems)
#define WS_PACKB  6400000
#define WS_PACKW2 (WS_PACKB + 131072)
#define WS_WN     (WS_PACKW2 + 32768)
#define WS_PW2    (WS_WN + 576)
#define WS_WNP    (WS_PW2 + 2048)

#define NB_U1 1563            // 64 points per block (16/wave, MFMA path)
#define NB_PACK 256
#define NB_PACKW2 64

__device__ __forceinline__ float lrelu(float x) { return fmaxf(x, 0.1f * x); }

// exact RNE (one-time prep only)
__device__ __forceinline__ u32 f2bf(float f) {
    union { float f; u32 u; } v; v.f = f;
    return (v.u + 0x7FFFu + ((v.u >> 16) & 1u)) >> 16;
}
// fast round-half-up, scalar
__device__ __forceinline__ u16 f2bfF(float f) {
    union { float f; u32 u; } v; v.f = f;
    return (u16)((v.u + 0x8000u) >> 16);
}
// fast round-half-up, packed pair (low=a, high=b)
__device__ __forceinline__ u32 pkbf(float a, float b) {
    union { float f; u32 u; } x, y; x.f = a; y.f = b;
    return __builtin_amdgcn_perm(y.u + 0x8000u, x.u + 0x8000u, 0x07060302u);
}
__device__ __forceinline__ float bf2f(u32 h) {
    union { u32 u; float f; } v; v.u = h << 16; return v.f;
}

// ---- merged prep: u1 feats via MFMA + pack lin_w/W2/pe_w2/W23 + fold WeightNet ----
__global__ __launch_bounds__(256) void k_prep(
    const float* __restrict__ df, const float* __restrict__ u1_w,
    const float* __restrict__ u1_b, u32* __restrict__ feats2,
    const float* __restrict__ lin_w, u16* __restrict__ packB,
    const float* __restrict__ u2_w, const float* __restrict__ sc_w,
    u16* __restrict__ packW2,
    const float* __restrict__ wn_w2, const float* __restrict__ wn_b2,
    const float* __restrict__ wn_w3, const float* __restrict__ wn_b3,
    float* __restrict__ wnf,
    const float* __restrict__ pe_w2, u16* __restrict__ pw2,
    u16* __restrict__ wnfp)
{
    int bid = blockIdx.x;
    if (bid < NB_U1) {
        // u1 GEMM: per wave, feats[16 pts][32 ch] = df[16][64] @ u1_w[64][32] + b.
        const int wv = threadIdx.x >> 6, lane = threadIdx.x & 63;
        const int quad = lane >> 4, nl = lane & 15;
        const int pbase = bid * 64 + wv * 16;
        if (pbase >= NPTS) return;

        bf16x8 bw[2][2];   // [nt][kk]
        #pragma unroll
        for (int nt = 0; nt < 2; ++nt)
            #pragma unroll
            for (int kk = 0; kk < 2; ++kk)
                #pragma unroll
                for (int j = 0; j < 8; ++j)
                    bw[nt][kk][j] = (short)f2bf(u1_w[(kk * 32 + quad * 8 + j) * CMID + nt * 16 + nl]);

        const float* arow = df + (size_t)(pbase + nl) * CIN + quad * 8;
        float4 a0 = *(const float4*)(arow + 0);
        float4 a1 = *(const float4*)(arow + 4);
        float4 a2 = *(const float4*)(arow + 32);
        float4 a3 = *(const float4*)(arow + 36);
        bf16x8 afr0, afr1;
        u32* ap0 = (u32*)&afr0; u32* ap1 = (u32*)&afr1;
        ap0[0] = pkbf(a0.x, a0.y); ap0[1] = pkbf(a0.z, a0.w);
        ap0[2] = pkbf(a1.x, a1.y); ap0[3] = pkbf(a1.z, a1.w);
        ap1[0] = pkbf(a2.x, a2.y); ap1[1] = pkbf(a2.z, a2.w);
        ap1[2] = pkbf(a3.x, a3.y); ap1[3] = pkbf(a3.z, a3.w);

        const f32x4 z = {0.f, 0.f, 0.f, 0.f};
        f32x4 acc0 = z, acc1 = z;
        acc0 = __builtin_amdgcn_mfma_f32_16x16x32_bf16(afr0, bw[0][0], acc0, 0, 0, 0);
        acc0 = __builtin_amdgcn_mfma_f32_16x16x32_bf16(afr1, bw[0][1], acc0, 0, 0, 0);
        acc1 = __builtin_amdgcn_mfma_f32_16x16x32_bf16(afr0, bw[1][0], acc1, 0, 0, 0);
        acc1 = __builtin_amdgcn_mfma_f32_16x16x32_bf16(afr1, bw[1][1], acc1, 0, 0, 0);

        float blo = u1_b[nl], bhi = u1_b[16 + nl];
        #pragma unroll
        for (int r = 0; r < 4; ++r) {
            int pt = pbase + quad * 4 + r;
            feats2[(size_t)pt * 16 + nl] = f2bf(acc0[r] + blo) | (f2bf(acc1[r] + bhi) << 16);
        }
    } else if (bid < NB_U1 + NB_PACK) {
        int t = (bid - NB_U1) * 256 + threadIdx.x;     // 65536 total
        int j = t & 7, ln = (t >> 3) & 63, s = t >> 9;
        int nt = s & 3, kb = s >> 2;
        int k = kb * 32 + (ln >> 4) * 8 + j;
        int n = nt * 16 + (ln & 15);
        packB[t] = (u16)f2bf(lin_w[k * 64 + n]);
    } else if (bid < NB_U1 + NB_PACK + NB_PACKW2) {
        int t = (bid - NB_U1 - NB_PACK) * 256 + threadIdx.x;   // 16384 total
        int j = t & 7, ln = (t >> 3) & 63, s = t >> 9;
        int nt2 = s & 7, kb2 = s >> 3;
        int k = kb2 * 32 + (ln >> 4) * 8 + j;
        int n = nt2 * 16 + (ln & 15);
        float v = (k < 64) ? u2_w[k * COUT + n] : sc_w[(k - 64) * COUT + n];
        packW2[t] = (u16)f2bf(v);
    } else if (bid == NB_U1 + NB_PACK + NB_PACKW2) {
        int t = threadIdx.x;
        if (t < 128) {
            int i = t >> 4, o = t & 15;
            float a = 0.f;
            #pragma unroll
            for (int m = 0; m < 8; ++m) a += wn_w2[i * 8 + m] * wn_w3[m * 16 + o];
            wnf[i * 16 + o] = a;
        } else if (t < 144) {
            int o = t - 128;
            float a = wn_b3[o];
            #pragma unroll
            for (int m = 0; m < 8; ++m) a += wn_b2[m] * wn_w3[m * 16 + o];
            wnf[128 + o] = a;
        }
    } else {
        int t = threadIdx.x;
        // pack pe_w2 into B2 A-frag order: pw2[ct*512+quad*128+nl*8+j]
        for (int e = t; e < 1024; e += 256) {
            int j = e & 7, nl2 = (e >> 3) & 15, qd = (e >> 7) & 3, ct = e >> 9;
            pw2[e] = (u16)f2bf(pe_w2[(qd * 8 + j) * 32 + nl2 + 16 * ct]);
        }
        // pack folded W23^T A-frag: wnfp[nl*8+j] = bf(W23[j][nl]) (recomputed,
        // not read from wnf — avoids cross-block ordering in this kernel)
        if (t < 128) {
            int nl2 = t >> 3, j = t & 7;
            float a = 0.f;
            #pragma unroll
            for (int m = 0; m < 8; ++m) a += wn_w2[j * 8 + m] * wn_w3[m * 16 + nl2];
            wnfp[t] = (u16)f2bf(a);
        }
    }
}

// ---- Fused: gather/PE/WN/einsum (phase 1) + GEMM1 + GEMM2 (phase 2). ----
// Block = 256 threads = 16 points; one wave handles 4 points in phase 1.
// LDS 40,192 B (4 blocks/CU): loc/h1/idx live in registers (ds_bpermute moves);
// WeightNet fold + PE layer2 are MFMAs with pre-packed bf16 weights.
__global__ __launch_bounds__(256) void k_fused(
    const float* __restrict__ xyz, const int* __restrict__ nei,
    const u32* __restrict__ feats2,
    const float* __restrict__ pe_w1, const float* __restrict__ pe_b1,
    const float* __restrict__ pe_b2,
    const float* __restrict__ wn_w1, const float* __restrict__ wn_b1,
    const float* __restrict__ wnf,
    const u16* __restrict__ pw2, const u16* __restrict__ wnfp,
    const u16* __restrict__ packB, const u16* __restrict__ packW2,
    const float* __restrict__ lin_b,
    const float* __restrict__ u2_b, const float* __restrict__ sc_b,
    const float* __restrict__ df, float* __restrict__ out,
    float* __restrict__ locout)
{
    __shared__ __align__(16) u16 aggL[16 * APITCH];   // 33,024 B
    __shared__ __align__(16) u16 pexd[4][32][16];     //  4,096 B; pe in ph1, xd in ph2
    __shared__ __align__(16) u16 w_s[4][16][24];      //  3,072 B (wave-private, pitch 24)

    u16* xd = &pexd[0][0][0];                         // phase-2 alias (4 KB, exact)

    const int tid = threadIdx.x, wv = tid >> 6, lane = tid & 63;
    const int quad = lane >> 4, nl = lane & 15;
    const int p0 = blockIdx.x * 16;
    const int ptBase = p0 + wv * 4;

    // ---- phase 1, step 0: coords + indices + h1 (lane: point=quad, k=nl) ----
    // loc, h1, idx stay in REGISTERS; consumers fetch per-p via ds_bpermute.
    int pt0 = ptBase + quad;
    int idx0 = nei[pt0 * KNEI + nl];
    float lx0, ly0, lz0;
    uint4 hp;
    {
        float cx = xyz[pt0 * 3 + 0], cy = xyz[pt0 * 3 + 1], cz = xyz[pt0 * 3 + 2];
        lx0 = xyz[idx0 * 3 + 0] - cx;
        ly0 = xyz[idx0 * 3 + 1] - cy;
        lz0 = xyz[idx0 * 3 + 2] - cz;
        float3 lv; lv.x = lx0; lv.y = ly0; lv.z = lz0;
        *(float3*)(locout + (size_t)(pt0 * KNEI + nl) * 3) = lv;
        // WeightNet layer-1 (only nonlinearity before the fold), bf16-packed
        u32* hpp = (u32*)&hp;
        #pragma unroll
        for (int h = 0; h < 8; h += 2) {
            float a = lrelu(wn_b1[h]     + lx0 * wn_w1[h]     + ly0 * wn_w1[8 + h]     + lz0 * wn_w1[16 + h]);
            float b = lrelu(wn_b1[h + 1] + lx0 * wn_w1[h + 1] + ly0 * wn_w1[8 + h + 1] + lz0 * wn_w1[16 + h + 1]);
            hpp[h >> 1] = pkbf(a, b);
        }
    }

    // ---- preload per-lane weights (pre-packed bf16: no conversions) ----
    float w1r0[8], w1r1[8], w1r2[8], b1v[8];
    #pragma unroll
    for (int j = 0; j < 8; ++j) {
        int h = quad * 8 + j;
        w1r0[j] = pe_w1[h]; w1r1[j] = pe_w1[32 + h]; w1r2[j] = pe_w1[64 + h];
        b1v[j] = pe_b1[h];
    }
    bf16x8 w2t[2];
    w2t[0] = *(const bf16x8*)(pw2 + (quad * 16 + nl) * 8);
    w2t[1] = *(const bf16x8*)(pw2 + (64 + quad * 16 + nl) * 8);
    f32x4 b2c[2];                       // pe_b2 rides the MFMA C operand
    #pragma unroll
    for (int ct = 0; ct < 2; ++ct)
        #pragma unroll
        for (int r = 0; r < 4; ++r)
            b2c[ct][r] = pe_b2[16 * ct + quad * 4 + r];
    bf16x8 wnfA = 0;                    // fold A-frag (quad0 rows h<8)
    if (quad == 0) wnfA = *(const bf16x8*)(wnfp + nl * 8);
    f32x4 b23c;                         // fold bias rides the MFMA C operand
    #pragma unroll
    for (int r = 0; r < 4; ++r) b23c[r] = wnf[128 + quad * 4 + r];

    const f32x4 zacc = {0.f, 0.f, 0.f, 0.f};
    const int jb = (quad & 1) * 8;      // k-halves mirrored across quad pairs

    for (int p = 0; p < 4; ++p) {
        const int m = wv * 4 + p;   // block-local point row
        const int pidx = (p * 16 + nl) << 2;   // bpermute byte idx: lane p*16+nl

        // ---- idx pull (all lanes active: sources 0..63 all live) ----
        int idkv[8];
        #pragma unroll
        for (int j = 0; j < 8; ++j)
            idkv[j] = __builtin_amdgcn_ds_bpermute((p * 16 + jb + j) << 2, idx0);

        // ---- paired feats gather into B-frags via v_perm (quads 0,1; 2,3 zero) ----
        bf16x8 featf0 = 0, featf1 = 0;
        if (quad < 2) {
            u32 gv[8];
            #pragma unroll
            for (int j = 0; j < 8; ++j)
                gv[j] = feats2[(size_t)idkv[j] * 16 + nl];
            u32* f0w = (u32*)&featf0;
            u32* f1w = (u32*)&featf1;
            #pragma unroll
            for (int jp = 0; jp < 4; ++jp) {
                u32 a = gv[2 * jp], b = gv[2 * jp + 1];
                f0w[jp] = __builtin_amdgcn_perm(b, a, 0x05040100u);   // lo16(a)|lo16(b)<<16
                f1w[jp] = __builtin_amdgcn_perm(b, a, 0x07060302u);   // hi16(a)|hi16(b)<<16
            }
        }

        // ---- loc for (point p, k=nl) pulled cross-lane (all lanes active) ----
        float lx = __int_as_float(__builtin_amdgcn_ds_bpermute(pidx, __float_as_int(lx0)));
        float ly = __int_as_float(__builtin_amdgcn_ds_bpermute(pidx, __float_as_int(ly0)));
        float lz = __int_as_float(__builtin_amdgcn_ds_bpermute(pidx, __float_as_int(lz0)));

        // ---- h1 B-frag: B[h=quad*8+j][k=nl] = h1[p][nl][j]; quads 1-3 zero ----
        u32 hb0 = (u32)__builtin_amdgcn_ds_bpermute(pidx, (int)hp.x);
        u32 hb1 = (u32)__builtin_amdgcn_ds_bpermute(pidx, (int)hp.y);
        u32 hb2 = (u32)__builtin_amdgcn_ds_bpermute(pidx, (int)hp.z);
        u32 hb3 = (u32)__builtin_amdgcn_ds_bpermute(pidx, (int)hp.w);
        bf16x8 h1B = 0;
        if (quad == 0) {
            u32* hb = (u32*)&h1B;
            hb[0] = hb0; hb[1] = hb1; hb[2] = hb2; hb[3] = hb3;
        }

        // ---- B1: ph in B-frag layout (h=quad*8+j, k_nei=nl) ----
        bf16x8 phf;
        {
            u32* ph32 = (u32*)&phf;
            #pragma unroll
            for (int j = 0; j < 8; j += 2) {
                float v0 = lrelu(b1v[j]     + lx * w1r0[j]     + ly * w1r1[j]     + lz * w1r2[j]);
                float v1 = lrelu(b1v[j + 1] + lx * w1r0[j + 1] + ly * w1r1[j + 1] + lz * w1r2[j + 1]);
                ph32[j >> 1] = pkbf(v0, v1);
            }
        }

        // ---- B2: pe^T = w2^T @ ph + b2 : 2 MFMAs (bias in C) ----
        f32x4 pe0 = __builtin_amdgcn_mfma_f32_16x16x32_bf16(w2t[0], phf, b2c[0], 0, 0, 0);
        f32x4 pe1 = __builtin_amdgcn_mfma_f32_16x16x32_bf16(w2t[1], phf, b2c[1], 0, 0, 0);

        #pragma unroll
        for (int r = 0; r < 4; ++r) {
            pexd[wv][quad * 4 + r][nl]      = f2bfF(lrelu(pe0[r]));
            pexd[wv][16 + quad * 4 + r][nl] = f2bfF(lrelu(pe1[r]));
        }

        // ---- folded WeightNet via MFMA: w[o][k] = lrelu(wnf^T @ h1 + b23) ----
        {
            f32x4 wacc = __builtin_amdgcn_mfma_f32_16x16x32_bf16(wnfA, h1B, b23c, 0, 0, 0);
            #pragma unroll
            for (int r = 0; r < 4; ++r)
                w_s[wv][quad * 4 + r][nl] = f2bfF(lrelu(wacc[r]));
        }
        // wave-private LDS: intra-wave ordering via lgkmcnt; no block barrier.

        // ---- read frags: wA (A: o=nl, k=quad*8+j), peB (B: k, c=nl) ----
        bf16x8 wA = 0, peB0 = 0, peB1 = 0;
        if (quad < 2) {
            wA   = *(const bf16x8*)&w_s[wv][nl][quad * 8];
            peB0 = *(const bf16x8*)&pexd[wv][nl][quad * 8];
            peB1 = *(const bf16x8*)&pexd[wv][nl + 16][quad * 8];
        }

        // ---- einsum: D[o][c] = w^T @ nf, 4 c-tiles, K=16 (padded) ----
        f32x4 c0a = __builtin_amdgcn_mfma_f32_16x16x32_bf16(wA, featf0, zacc, 0, 0, 0);
        f32x4 c1a = __builtin_amdgcn_mfma_f32_16x16x32_bf16(wA, featf1, zacc, 0, 0, 0);
        f32x4 c2a = __builtin_amdgcn_mfma_f32_16x16x32_bf16(wA, peB0, zacc, 0, 0, 0);
        f32x4 c3a = __builtin_amdgcn_mfma_f32_16x16x32_bf16(wA, peB1, zacc, 0, 0, 0);

        // ---- store agg row into LDS (plain layout, pitch 1032) ----
        {
            u16* arow = aggL + m * APITCH;
            f32x4 cc[4] = {c0a, c1a, c2a, c3a};
            #pragma unroll
            for (int ct = 0; ct < 4; ++ct) {
                int e = (nl + 16 * ct) * 16 + quad * 4;
                uint2 o;
                o.x = pkbf(cc[ct][0], cc[ct][1]);
                o.y = pkbf(cc[ct][2], cc[ct][3]);
                *(uint2*)(arow + e) = o;
            }
        }
    }
    __syncthreads();   // all aggL rows visible; pe region now dead -> xd

    // ================= phase 2 =================
    // GEMM1: x[16][64] = lrelu(agg @ lin_w + lin_b); wave wv owns n-tile nt=wv.
    const int nt = wv;
    {
        const u16* bp = packB + nt * 512 + lane * 8;
        const u16* arow = aggL + nl * APITCH;
        f32x4 accA = zacc, accB = zacc;
        #pragma unroll
        for (int kk = 0; kk < 16; ++kk) {
            int kbA = 2 * kk, kbB = 2 * kk + 1;
            bf16x8 aA = *(const bf16x8*)(arow + (4 * kbA + quad) * 8);
            bf16x8 aB = *(const bf16x8*)(arow + (4 * kbB + quad) * 8);
            bf16x8 bA = *(const bf16x8*)(bp + kbA * 2048);
            bf16x8 bB = *(const bf16x8*)(bp + kbB * 2048);
            accA = __builtin_amdgcn_mfma_f32_16x16x32_bf16(aA, bA, accA, 0, 0, 0);
            accB = __builtin_amdgcn_mfma_f32_16x16x32_bf16(aB, bB, accB, 0, 0, 0);
        }
        int col = nt * 16 + nl;
        float lb = lin_b[col];
        int kb2 = col >> 5, q2 = (col >> 3) & 3, j2 = col & 7;
        #pragma unroll
        for (int r = 0; r < 4; ++r) {
            int mm = quad * 4 + r;
            float v = lrelu(accA[r] + accB[r] + lb);
            xd[(kb2 * 64 + q2 * 16 + mm) * 8 + j2] = f2bfF(v);
        }
    }
    // df -> xd (cols 64..127)
    if (tid < 128) {
        int mm = tid >> 3, cg = tid & 7;
        int colk = 64 + cg * 8;
        const float* dfr = df + (size_t)(p0 + mm) * CIN + cg * 8;
        float4 f0 = *(const float4*)(dfr);
        float4 f1 = *(const float4*)(dfr + 4);
        int kb2 = colk >> 5, q2 = (colk >> 3) & 3;
        uint4 o;
        o.x = pkbf(f0.x, f0.y);
        o.y = pkbf(f0.z, f0.w);
        o.z = pkbf(f1.x, f1.y);
        o.w = pkbf(f1.z, f1.w);
        *(uint4*)(xd + (kb2 * 64 + q2 * 16 + mm) * 8) = o;
    }
    __syncthreads();

    // GEMM2: out[16][128] = lrelu([x|df] @ W2 + u2_b + sc_b); wave owns 2 n-tiles
    {
        f32x4 acc20 = zacc, acc21 = zacc;
        #pragma unroll
        for (int kb = 0; kb < 4; ++kb) {
            bf16x8 a = *(const bf16x8*)(xd + (kb * 64 + lane) * 8);
            bf16x8 b0 = *(const bf16x8*)(packW2 + (size_t)(kb * 8 + wv * 2 + 0) * 512 + lane * 8);
            bf16x8 b1 = *(const bf16x8*)(packW2 + (size_t)(kb * 8 + wv * 2 + 1) * 512 + lane * 8);
            acc20 = __builtin_amdgcn_mfma_f32_16x16x32_bf16(a, b0, acc20, 0, 0, 0);
            acc21 = __builtin_amdgcn_mfma_f32_16x16x32_bf16(a, b1, acc21, 0, 0, 0);
        }
        #pragma unroll
        for (int t = 0; t < 2; ++t) {
            f32x4 ac = t ? acc21 : acc20;
            int colo = (wv * 2 + t) * 16 + nl;
            float bias = u2_b[colo] + sc_b[colo];
            #pragma unroll
            for (int r = 0; r < 4; ++r) {
                int mm = quad * 4 + r;
                out[(size_t)(p0 + mm) * COUT + colo] = lrelu(ac[r] + bias);
            }
        }
    }
}

extern "C" void kernel_launch(void* const* d_in, const int* in_sizes, int n_in,
                              void* d_out, int out_size, void* d_ws, size_t ws_size,
                              hipStream_t stream) {
    const float* xyz   = (const float*)d_in[0];
    const float* df    = (const float*)d_in[1];
    const int*   nei   = (const int*)d_in[2];
    const float* pe_w1 = (const float*)d_in[3];
    const float* pe_b1 = (const float*)d_in[4];
    const float* pe_w2 = (const float*)d_in[5];
    const float* pe_b2 = (const float*)d_in[6];
    const float* u1_w  = (const float*)d_in[7];
    const float* u1_b  = (const float*)d_in[8];
    const float* wn_w1 = (const float*)d_in[9];
    const float* wn_b1 = (const float*)d_in[10];
    const float* wn_w2 = (const float*)d_in[11];
    const float* wn_b2 = (const float*)d_in[12];
    const float* wn_w3 = (const float*)d_in[13];
    const float* wn_b3 = (const float*)d_in[14];
    const float* lin_w = (const float*)d_in[15];
    const float* lin_b = (const float*)d_in[16];
    const float* u2_w  = (const float*)d_in[17];
    const float* u2_b  = (const float*)d_in[18];
    const float* sc_w  = (const float*)d_in[19];
    const float* sc_b  = (const float*)d_in[20];

    u32* feats2 = (u32*)d_ws;
    u16* packB  = (u16*)((char*)d_ws + WS_PACKB);
    u16* packW2 = (u16*)((char*)d_ws + WS_PACKW2);
    float* wnf  = (float*)((char*)d_ws + WS_WN);
    u16* pw2    = (u16*)((char*)d_ws + WS_PW2);
    u16* wnfp   = (u16*)((char*)d_ws + WS_WNP);
    float* outp = (float*)d_out;
    float* locout = outp + (size_t)NPTS * COUT;

    hipLaunchKernelGGL(k_prep, dim3(NB_U1 + NB_PACK + NB_PACKW2 + 2), dim3(256), 0, stream,
                       df, u1_w, u1_b, feats2, lin_w, packB, u2_w, sc_w, packW2,
                       wn_w2, wn_b2, wn_w3, wn_b3, wnf, pe_w2, pw2, wnfp);

    hipLaunchKernelGGL(k_fused, dim3(NPTS / 16), dim3(256), 0, stream,
                       xyz, nei, feats2,
                       pe_w1, pe_b1, pe_b2,
                       wn_w1, wn_b1, wnf, pw2, wnfp,
                       packB, packW2, lin_b, u2_b, sc_b,
                       df, outp, locout);
}